// Round 3
// baseline (398.530 us; speedup 1.0000x reference)
//
#include <hip/hip_runtime.h>

// ---------------------------------------------------------------------------
// N=400000, E=2000000, B=8, C_IN=4, N_EDGE_TYPE=5, N_NODE_TYPE=7, C_OUT=32.
//
// HW model (measured; rounds 0-2):
//  - Global atomics into 88MB fp32 thrash L2 -> 504us (R1 here). DEAD END.
//  - Sort pipeline: consume @ 37% occ still latency-bound (VALU 15%, HBM 15%)
//    on 2M random x[col] gathers (FETCH 77MB >> 25MB streaming; x=6.4MB >
//    4MB/XCD L2).
//  => R3: scatter gathers x[col] (it already gathers ntype[col]) and writes
//     value-carrying records {meta u32, val float4}; consume becomes pure
//     streaming + LDS atomics + dense mix. temb chain fused to ONE 8-block
//     kernel (no memset, no global atomics). 13 -> 9 dispatches.
// ---------------------------------------------------------------------------

#define CH     2048        // edges per chunk
#define BSZ    128         // nodes per bucket
#define BSH    7           // log2(BSZ)
#define NBMAX  4096        // max buckets (N <= 524288)

// ---- temb fused: per-batch block computes emb->h1->h2->inj ----------------
__global__ __launch_bounds__(256) void temb_fused_kernel(
    const float* __restrict__ t,
    const float* __restrict__ W1, const float* __restrict__ b1,
    const float* __restrict__ W2, const float* __restrict__ b2,
    const float* __restrict__ Wt, float* __restrict__ inj)
{
    int b = blockIdx.x;
    int tid = threadIdx.x;
    __shared__ float emb[128];
    __shared__ float s1[512];
    __shared__ float s2[512];
    __shared__ float red[256];
    float tv = t[b];
    if (tid < 128) {
        const float kStep = 9.210340371976184f / 63.0f;
        int k = tid & 63;
        float ang = tv * expf(-(float)k * kStep);
        emb[tid] = (tid < 64) ? sinf(ang) : cosf(ang);
    }
    __syncthreads();
    // h1 = swish(emb @ W1 + b1): each thread covers j = tid, tid+256
    {
        float a0 = 0.f, a1 = 0.f;
        for (int k = 0; k < 128; ++k) {
            float e = emb[k];
            a0 += e * W1[k * 512 + tid];
            a1 += e * W1[k * 512 + tid + 256];
        }
        float v0 = a0 + b1[tid], v1 = a1 + b1[tid + 256];
        s1[tid]       = v0 / (1.0f + expf(-v0));
        s1[tid + 256] = v1 / (1.0f + expf(-v1));
    }
    __syncthreads();
    // h2 = h1s @ W2 + b2; s2 = swish(h2)
    {
        float a0 = 0.f, a1 = 0.f;
        for (int k = 0; k < 512; ++k) {
            float e = s1[k];
            a0 += e * W2[k * 512 + tid];
            a1 += e * W2[k * 512 + tid + 256];
        }
        float v0 = a0 + b2[tid], v1 = a1 + b2[tid + 256];
        s2[tid]       = v0 / (1.0f + expf(-v0));
        s2[tid + 256] = v1 / (1.0f + expf(-v1));
    }
    __syncthreads();
    // inj[b] = s2 @ Wt : 32 cols x 8 k-segments
    {
        int c = tid & 31, seg = tid >> 5;
        float acc = 0.f;
        int k0 = seg * 64;
        for (int k = k0; k < k0 + 64; ++k)
            acc += s2[k] * Wt[k * 32 + c];
        red[tid] = acc;
        __syncthreads();
        if (tid < 32) {
            float s = 0.f;
#pragma unroll
            for (int g = 0; g < 8; ++g) s += red[g * 32 + tid];
            inj[b * 32 + tid] = s;
        }
    }
}

// ---- legacy temb kernels (fallback path only) -----------------------------
__global__ __launch_bounds__(64) void temb1_kernel(
    const float* __restrict__ t, const float* __restrict__ W1,
    float* __restrict__ h1acc)
{
    int jb = blockIdx.x & 7, ks = blockIdx.x >> 3;
    __shared__ float embs[8][32];
    int tid = threadIdx.x;
    const float kStep = 9.210340371976184f / 63.0f;
    for (int i = tid; i < 256; i += 64) {
        int b = i >> 5, kk = i & 31;
        int k = ks * 32 + kk;
        float v;
        if (k < 64) v = sinf(t[b] * expf(-(float)k * kStep));
        else        v = cosf(t[b] * expf(-(float)(k - 64) * kStep));
        embs[b][kk] = v;
    }
    __syncthreads();
    int j = jb * 64 + tid;
    float acc[8] = {};
    for (int kk = 0; kk < 32; ++kk) {
        float w = W1[(ks * 32 + kk) * 512 + j];
#pragma unroll
        for (int b = 0; b < 8; ++b) acc[b] += embs[b][kk] * w;
    }
#pragma unroll
    for (int b = 0; b < 8; ++b) atomicAdd(&h1acc[b * 512 + j], acc[b]);
}

__global__ __launch_bounds__(64) void temb2_kernel(
    const float* __restrict__ h1acc, const float* __restrict__ b1,
    const float* __restrict__ W2, float* __restrict__ h2acc)
{
    int jb = blockIdx.x & 7, ks = blockIdx.x >> 3;
    __shared__ float h1s[8][64];
    int tid = threadIdx.x;
    for (int i = tid; i < 512; i += 64) {
        int b = i >> 6, kk = i & 63;
        int k = ks * 64 + kk;
        float v = h1acc[b * 512 + k] + b1[k];
        h1s[b][kk] = v / (1.0f + expf(-v));
    }
    __syncthreads();
    int j = jb * 64 + tid;
    float acc[8] = {};
    for (int kk = 0; kk < 64; ++kk) {
        float w = W2[(ks * 64 + kk) * 512 + j];
#pragma unroll
        for (int b = 0; b < 8; ++b) acc[b] += h1s[b][kk] * w;
    }
#pragma unroll
    for (int b = 0; b < 8; ++b) atomicAdd(&h2acc[b * 512 + j], acc[b]);
}

__global__ __launch_bounds__(256) void temb3_kernel(
    const float* __restrict__ h2acc, const float* __restrict__ b2,
    const float* __restrict__ Wt, float* __restrict__ inj)
{
    int ks = blockIdx.x;
    __shared__ float sws[8][64];
    int tid = threadIdx.x;
    for (int i = tid; i < 512; i += 256) {
        int b = i >> 6, kk = i & 63;
        int k = ks * 64 + kk;
        float v = h2acc[b * 512 + k] + b2[k];
        sws[b][kk] = v / (1.0f + expf(-v));
    }
    __syncthreads();
    int b = tid >> 5, c = tid & 31;
    float acc = 0.f;
    for (int kk = 0; kk < 64; ++kk)
        acc += sws[b][kk] * Wt[(ks * 64 + kk) * 32 + c];
    atomicAdd(&inj[tid], acc);
}

// ---- hist: block per chunk (padded to NCHP); LDS histogram ----------------
__global__ __launch_bounds__(256) void hist_kernel(
    const int* __restrict__ ei, int* __restrict__ counts, int E, int NB)
{
    __shared__ int h[NBMAX];
    int tid = threadIdx.x;
    int c = blockIdx.x;
    for (int i = tid; i < NB; i += 256) h[i] = 0;
    __syncthreads();
    int s = c * CH, e = min(s + CH, E);
    for (int i = s + tid; i < e; i += 256)
        atomicAdd(&h[ei[i] >> BSH], 1);
    __syncthreads();
    int* row = counts + (size_t)c * NB;
    for (int i = tid; i < NB; i += 256) row[i] = h[i];
}

// ---- transpose: out[c*R + r] = in[r*C + c]; in is [R][C] ------------------
__global__ __launch_bounds__(256) void transpose_kernel(
    const int* __restrict__ in, int* __restrict__ outp, int R, int C)
{
    __shared__ int tile[32][33];
    int c0 = blockIdx.x * 32, r0 = blockIdx.y * 32;
    int tx = threadIdx.x & 31, ty = threadIdx.x >> 5;   // 32x8
#pragma unroll
    for (int k = 0; k < 4; ++k) {
        int r = r0 + ty + k * 8, c = c0 + tx;
        if (r < R && c < C) tile[ty + k * 8][tx] = in[(size_t)r * C + c];
    }
    __syncthreads();
#pragma unroll
    for (int k = 0; k < 4; ++k) {
        int c = c0 + ty + k * 8, r = r0 + tx;
        if (r < R && c < C) outp[(size_t)c * R + r] = tile[tx][ty + k * 8];
    }
}

// ---- scanA: per-block sums over linear countsT (bucket-major) -------------
__global__ __launch_bounds__(256) void scanA_kernel(
    const int* __restrict__ countsT, int* __restrict__ bsums, int M)
{
    __shared__ int s[256];
    int tid = threadIdx.x;
    int j0 = blockIdx.x * 4096 + tid * 16;
    int p = 0;
#pragma unroll
    for (int k = 0; k < 16; ++k) {
        int j = j0 + k;
        if (j < M) p += countsT[j];
    }
    s[tid] = p; __syncthreads();
    for (int off = 128; off > 0; off >>= 1) {
        if (tid < off) s[tid] += s[tid + off];
        __syncthreads();
    }
    if (tid == 0) bsums[blockIdx.x] = s[0];
}

// ---- scanB: exclusive scan of block sums (single block, <=1024) -----------
__global__ __launch_bounds__(1024) void scanB_kernel(
    int* __restrict__ bsums, int* __restrict__ bstart, int nblk, int NB, int E)
{
    __shared__ int s[1024];
    int tid = threadIdx.x;
    int v = (tid < nblk) ? bsums[tid] : 0;
    s[tid] = v; __syncthreads();
    for (int off = 1; off < 1024; off <<= 1) {
        int u = (tid >= off) ? s[tid - off] : 0;
        __syncthreads();
        s[tid] += u;
        __syncthreads();
    }
    if (tid < nblk) bsums[tid] = s[tid] - v;          // exclusive
    if (tid == 0) bstart[NB] = E;
}

// ---- scanC: exact base for every (bucket, chunk) region + bstart ----------
__global__ __launch_bounds__(256) void scanC_kernel(
    const int* __restrict__ countsT, const int* __restrict__ bsums,
    int* __restrict__ base, int* __restrict__ bstart, int M, int LOGC)
{
    __shared__ int s[256];
    int tid = threadIdx.x;
    int j0 = blockIdx.x * 4096 + tid * 16;
    int v[16]; int p = 0;
#pragma unroll
    for (int k = 0; k < 16; ++k) {
        int j = j0 + k;
        v[k] = (j < M) ? countsT[j] : 0;
        p += v[k];
    }
    s[tid] = p; __syncthreads();
    for (int off = 1; off < 256; off <<= 1) {
        int u = (tid >= off) ? s[tid - off] : 0;
        __syncthreads();
        s[tid] += u;
        __syncthreads();
    }
    int run = bsums[blockIdx.x] + (s[tid] - p);
    int maskC = (1 << LOGC) - 1;
#pragma unroll
    for (int k = 0; k < 16; ++k) {
        int j = j0 + k;
        if (j < M) {
            base[j] = run;
            if ((j & maskC) == 0) bstart[j >> LOGC] = run;
            run += v[k];
        }
    }
}

// ---- scatter: block per chunk; XCD swizzle; gathers x[col]+ntype[col] -----
// recMeta = lrow | T<<7 | nt<<10 ; recVal = x[col] (float4)
__global__ __launch_bounds__(256) void scatter_kernel(
    const int* __restrict__ ei, const int* __restrict__ etype,
    const int* __restrict__ ntype, const float* __restrict__ x,
    const int* __restrict__ baseT,
    unsigned* __restrict__ recMeta, float4* __restrict__ recVal,
    int E, int NB)
{
    __shared__ int cur[NBMAX];
    int tid = threadIdx.x;
    // bijective XCD swizzle: consecutive chunks -> same XCD so co-writers of
    // each rec line share one XCD's L2 (no cross-XCD line bounce).
    int nwg = gridDim.x;
    int q = nwg >> 3, r = nwg & 7;
    int xcd = blockIdx.x & 7, idx = blockIdx.x >> 3;
    int c = (xcd < r) ? xcd * (q + 1) + idx
                      : r * (q + 1) + (xcd - r) * q + idx;
    for (int b = tid; b < NB; b += 256)
        cur[b] = baseT[(size_t)c * NB + b];
    __syncthreads();
    int s = c * CH, e = min(s + CH, E);
    for (int i = s + tid; i < e; i += 256) {
        int row = ei[i], col = ei[E + i];
        int T = etype[i], nt = ntype[col];
        float4 xv = ((const float4*)x)[col];
        int b = row >> BSH;
        int slot = atomicAdd(&cur[b], 1);
        recMeta[slot] = (unsigned)(row & (BSZ - 1)) |
                        ((unsigned)T << 7) | ((unsigned)nt << 10);
        recVal[slot] = xv;
    }
}

// ---- consume: streaming records; 5 LDS atomics/edge; dense mix ------------
__global__ __launch_bounds__(256) void consume_kernel(
    const int* __restrict__ bstart, const unsigned* __restrict__ recMeta,
    const float4* __restrict__ recVal, const float* __restrict__ Wc,
    const int* __restrict__ batch, const float* __restrict__ inj,
    float* __restrict__ out, int N)
{
    __shared__ float tile[BSZ * 57];   // row stride 57 (odd -> spread banks)
    __shared__ float Ws[55 * 32];
    int tid = threadIdx.x;
    int b = blockIdx.x;
    for (int i = tid; i < 55 * 32; i += 256) Ws[i] = Wc[i];
    for (int i = tid; i < BSZ * 57; i += 256) tile[i] = 0.f;
    __syncthreads();

    int s = bstart[b], e = bstart[b + 1];
#pragma unroll 2
    for (int i = s + tid; i < e; i += 256) {
        unsigned m = recMeta[i];
        float4 xv = recVal[i];
        int lrow = (int)(m & (BSZ - 1));
        int T    = (int)((m >> 7) & 7);
        int nt   = (int)((m >> 10) & 7);
        float* tr = tile + lrow * 57 + T * 11;
        atomicAdd(tr + 0, xv.x);
        atomicAdd(tr + 1, xv.y);
        atomicAdd(tr + 2, xv.z);
        atomicAdd(tr + 3, xv.w);
        atomicAdd(tr + 4 + nt, 1.0f);
    }
    __syncthreads();

    int nodes = N - b * BSZ; if (nodes > BSZ) nodes = BSZ;
    for (int oi = tid; oi < nodes * 8; oi += 256) {
        int nl = oi >> 3, cq = oi & 7;
        int n = b * BSZ + nl;
        const float* ar = tile + nl * 57;
        float4 acc = {0.f, 0.f, 0.f, 0.f};
#pragma unroll 5
        for (int f = 0; f < 55; ++f) {
            float a = ar[f];
            float4 w = *(const float4*)(Ws + f * 32 + cq * 4);
            acc.x += a * w.x;
            acc.y += a * w.y;
            acc.z += a * w.z;
            acc.w += a * w.w;
        }
        int bb = batch[n];
        float4 iv = ((const float4*)inj)[bb * 8 + cq];
        float4 o;
        o.x = iv.x + 0.2f * acc.x;
        o.y = iv.y + 0.2f * acc.y;
        o.z = iv.z + 0.2f * acc.z;
        o.w = iv.w + 0.2f * acc.w;
        ((float4*)out)[(size_t)n * 8 + cq] = o;
    }
}

// ---- fallback (guards fail): out init + direct atomic scatter -------------
__global__ __launch_bounds__(256) void init_kernel(
    const int* __restrict__ batch_id, const float* __restrict__ inj,
    float4* __restrict__ out, int N)
{
    int gid = blockIdx.x * 256 + threadIdx.x;
    if (gid >= N * 8) return;
    int n = gid >> 3, q = gid & 7;
    int b = batch_id[n];
    out[gid] = ((const float4*)inj)[b * 8 + q];
}

__global__ __launch_bounds__(256) void edge_direct_kernel(
    const int* __restrict__ ei, const int* __restrict__ etype,
    const int* __restrict__ ntype, const float* __restrict__ x,
    const float* __restrict__ Wc, float* __restrict__ out, int E)
{
    __shared__ float Ws[55 * 32];
    for (int i = threadIdx.x; i < 55 * 32; i += 256) Ws[i] = Wc[i];
    __syncthreads();
    unsigned total = (unsigned)E * 32u;
    unsigned stride = gridDim.x * 256u;
    for (unsigned idx = blockIdx.x * 256u + threadIdx.x; idx < total;
         idx += stride) {
        int e = (int)(idx >> 5);
        int c = (int)(idx & 31);
        int row = ei[e];
        int col = ei[E + e];
        int T = etype[e];
        int nt = ntype[col];
        float4 xv = ((const float4*)x)[col];
        const float* wb = Ws + T * 352;
        float y = xv.x * wb[c] + xv.y * wb[32 + c] + xv.z * wb[64 + c] +
                  xv.w * wb[96 + c] + wb[(4 + nt) * 32 + c];
        atomicAdd(out + (size_t)row * 32 + c, y * 0.2f);
    }
}

extern "C" void kernel_launch(void* const* d_in, const int* in_sizes, int n_in,
                              void* d_out, int out_size, void* d_ws, size_t ws_size,
                              hipStream_t stream) {
    const float* x     = (const float*)d_in[0];   // [N,4]
    const float* t     = (const float*)d_in[1];   // [8]
    const int*   ei    = (const int*)d_in[2];     // [2,E]
    const int*   etype = (const int*)d_in[3];     // [E]
    const int*   ntype = (const int*)d_in[4];     // [N]
    const int*   batch = (const int*)d_in[5];     // [N]
    const float* Wc    = (const float*)d_in[6];   // [55,32]
    const float* W1    = (const float*)d_in[7];   // [128,512]
    const float* b1    = (const float*)d_in[8];   // [512]
    const float* W2    = (const float*)d_in[9];   // [512,512]
    const float* b2    = (const float*)d_in[10];  // [512]
    const float* Wt    = (const float*)d_in[11];  // [512,32]
    float* out = (float*)d_out;

    int E = in_sizes[3];
    int N = in_sizes[4];

    int NB  = (N + BSZ - 1) >> BSH;               // 128-node buckets
    int NCH = (E + CH - 1) / CH;                  // real edge chunks
    int NCHP = 1, LOGC = 0;                       // padded to pow2
    while (NCHP < NCH) { NCHP <<= 1; ++LOGC; }
    size_t M = (size_t)NB << LOGC;                // scan length
    int nblkA = (int)((M + 4095) / 4096);

    // ws layout (4-byte units)
    float* ws     = (float*)d_ws;
    float* h1acc  = ws;                           // 4096 (fallback only)
    float* h2acc  = ws + 4096;                    // 4096 (fallback only)
    float* inj    = ws + 8192;                    // 256
    int*   bufA   = (int*)(ws + 8448);            // M (counts, then base)
    int*   bufB   = bufA + M;                     // M (countsT, then baseT)
    int*   bsums  = bufB + M;                     // 1024
    int*   bstart = bsums + 1024;                 // NB+1
    size_t recOff = 8448 + 2 * M + 1024 + NB + 1;
    recOff = (recOff + 3) & ~(size_t)3;           // 16B align
    unsigned* recMeta = (unsigned*)(ws + recOff); // E words
    size_t rvOff = (recOff + (size_t)E + 3) & ~(size_t)3;
    float4* recVal = (float4*)(ws + rvOff);       // E * 16B

    size_t needBytes = (rvOff + 4 * (size_t)E) * 4;
    bool okay = (NB <= NBMAX) && (nblkA <= 1024) && (ws_size >= needBytes) &&
                (M < (size_t)1 << 30);

    if (okay) {
        temb_fused_kernel<<<8, 256, 0, stream>>>(t, W1, b1, W2, b2, Wt, inj);

        // counts[c][b] (chunk-major, coalesced writes)
        hist_kernel<<<NCHP, 256, 0, stream>>>(ei, bufA, E, NB);
        // countsT[b][c] (bucket-major, coalesced scan reads)
        transpose_kernel<<<dim3((NB + 31) / 32, (NCHP + 31) / 32),
                           dim3(256), 0, stream>>>(bufA, bufB, NCHP, NB);
        scanA_kernel<<<nblkA, 256, 0, stream>>>(bufB, bsums, (int)M);
        scanB_kernel<<<1, 1024, 0, stream>>>(bsums, bstart, nblkA, NB, E);
        // base[b][c] (linear writes) + bstart
        scanC_kernel<<<nblkA, 256, 0, stream>>>(bufB, bsums, bufA, bstart,
                                                (int)M, LOGC);
        // baseT[c][b] (coalesced cursor init in scatter)
        transpose_kernel<<<dim3((NCHP + 31) / 32, (NB + 31) / 32),
                           dim3(256), 0, stream>>>(bufA, bufB, NB, NCHP);
        scatter_kernel<<<NCH, 256, 0, stream>>>(ei, etype, ntype, x, bufB,
                                                recMeta, recVal, E, NB);
        consume_kernel<<<NB, 256, 0, stream>>>(bstart, recMeta, recVal, Wc,
                                               batch, inj, out, N);
    } else {
        hipMemsetAsync(d_ws, 0, 8448 * 4, stream);
        temb1_kernel<<<32, 64, 0, stream>>>(t, W1, h1acc);
        temb2_kernel<<<64, 64, 0, stream>>>(h1acc, b1, W2, h2acc);
        temb3_kernel<<<8, 256, 0, stream>>>(h2acc, b2, Wt, inj);
        init_kernel<<<(N * 8 + 255) / 256, 256, 0, stream>>>(
            batch, inj, (float4*)out, N);
        edge_direct_kernel<<<16384, 256, 0, stream>>>(
            ei, etype, ntype, x, Wc, out, E);
    }
}

// Round 4
// 349.487 us; speedup vs baseline: 1.1403x; 1.1403x over previous
//
#include <hip/hip_runtime.h>

// ---------------------------------------------------------------------------
// N=400000, E=2000000, B=8, C_IN=4, N_EDGE_TYPE=5, N_NODE_TYPE=7, C_OUT=32.
//
// HW model (measured, rounds 0-3):
//  - Global atomics into 88MB fp32 thrash L2: 504us. DEAD END (R1).
//  - Fine-bucket (128-node) scatter: regions 0.65 rec -> random sub-line
//    stores, write-allocate amplification (R3: WRITE 141MB for 40MB payload).
//    RULE: NB*NCH <= E/8 for merged rec writes.
//  - consume x[col] gather: ~50MB line traffic (x=6.4MB > 4MB/XCD L2,
//    ~60% hit rate), latency/random-BW bound (R2: 105us @ 1.2TB/s).
//  => R4: COARSE sort (2048-node buckets, regions ~42 rec -> writes merge;
//     scan M=50K, transposes deleted) + FUSED consume: in-LDS fine sort into
//     16 windows (hist16 -> cursor scatter into 104KB LDS rec buffer), then
//     per-window tile accumulate + dense mix. 9 dispatches.
// ---------------------------------------------------------------------------

#define CH      8192       // edges per chunk
#define CW      2048       // coarse bucket width (nodes)
#define CWSH    11         // log2(CW)
#define WSZ     128        // consume window (nodes)
#define NW      16         // windows per coarse bucket = CW/WSZ
#define NBCMAX  512        // max coarse buckets (N <= 1M)
#define RECMAX  13312      // LDS record capacity (104KB)

// ---- temb fused: per-batch block computes emb->h1->h2->inj ----------------
__global__ __launch_bounds__(256) void temb_fused_kernel(
    const float* __restrict__ t,
    const float* __restrict__ W1, const float* __restrict__ b1,
    const float* __restrict__ W2, const float* __restrict__ b2,
    const float* __restrict__ Wt, float* __restrict__ inj)
{
    int b = blockIdx.x;
    int tid = threadIdx.x;
    __shared__ float emb[128];
    __shared__ float s1[512];
    __shared__ float s2[512];
    __shared__ float red[256];
    float tv = t[b];
    if (tid < 128) {
        const float kStep = 9.210340371976184f / 63.0f;
        int k = tid & 63;
        float ang = tv * expf(-(float)k * kStep);
        emb[tid] = (tid < 64) ? sinf(ang) : cosf(ang);
    }
    __syncthreads();
    {
        float a0 = 0.f, a1 = 0.f;
        for (int k = 0; k < 128; ++k) {
            float e = emb[k];
            a0 += e * W1[k * 512 + tid];
            a1 += e * W1[k * 512 + tid + 256];
        }
        float v0 = a0 + b1[tid], v1 = a1 + b1[tid + 256];
        s1[tid]       = v0 / (1.0f + expf(-v0));
        s1[tid + 256] = v1 / (1.0f + expf(-v1));
    }
    __syncthreads();
    {
        float a0 = 0.f, a1 = 0.f;
        for (int k = 0; k < 512; ++k) {
            float e = s1[k];
            a0 += e * W2[k * 512 + tid];
            a1 += e * W2[k * 512 + tid + 256];
        }
        float v0 = a0 + b2[tid], v1 = a1 + b2[tid + 256];
        s2[tid]       = v0 / (1.0f + expf(-v0));
        s2[tid + 256] = v1 / (1.0f + expf(-v1));
    }
    __syncthreads();
    {
        int c = tid & 31, seg = tid >> 5;
        float acc = 0.f;
        int k0 = seg * 64;
        for (int k = k0; k < k0 + 64; ++k)
            acc += s2[k] * Wt[k * 32 + c];
        red[tid] = acc;
        __syncthreads();
        if (tid < 32) {
            float s = 0.f;
#pragma unroll
            for (int g = 0; g < 8; ++g) s += red[g * 32 + tid];
            inj[b * 32 + tid] = s;
        }
    }
}

// ---- legacy temb kernels (fallback path only) -----------------------------
__global__ __launch_bounds__(64) void temb1_kernel(
    const float* __restrict__ t, const float* __restrict__ W1,
    float* __restrict__ h1acc)
{
    int jb = blockIdx.x & 7, ks = blockIdx.x >> 3;
    __shared__ float embs[8][32];
    int tid = threadIdx.x;
    const float kStep = 9.210340371976184f / 63.0f;
    for (int i = tid; i < 256; i += 64) {
        int b = i >> 5, kk = i & 31;
        int k = ks * 32 + kk;
        float v;
        if (k < 64) v = sinf(t[b] * expf(-(float)k * kStep));
        else        v = cosf(t[b] * expf(-(float)(k - 64) * kStep));
        embs[b][kk] = v;
    }
    __syncthreads();
    int j = jb * 64 + tid;
    float acc[8] = {};
    for (int kk = 0; kk < 32; ++kk) {
        float w = W1[(ks * 32 + kk) * 512 + j];
#pragma unroll
        for (int b = 0; b < 8; ++b) acc[b] += embs[b][kk] * w;
    }
#pragma unroll
    for (int b = 0; b < 8; ++b) atomicAdd(&h1acc[b * 512 + j], acc[b]);
}

__global__ __launch_bounds__(64) void temb2_kernel(
    const float* __restrict__ h1acc, const float* __restrict__ b1,
    const float* __restrict__ W2, float* __restrict__ h2acc)
{
    int jb = blockIdx.x & 7, ks = blockIdx.x >> 3;
    __shared__ float h1s[8][64];
    int tid = threadIdx.x;
    for (int i = tid; i < 512; i += 64) {
        int b = i >> 6, kk = i & 63;
        int k = ks * 64 + kk;
        float v = h1acc[b * 512 + k] + b1[k];
        h1s[b][kk] = v / (1.0f + expf(-v));
    }
    __syncthreads();
    int j = jb * 64 + tid;
    float acc[8] = {};
    for (int kk = 0; kk < 64; ++kk) {
        float w = W2[(ks * 64 + kk) * 512 + j];
#pragma unroll
        for (int b = 0; b < 8; ++b) acc[b] += h1s[b][kk] * w;
    }
#pragma unroll
    for (int b = 0; b < 8; ++b) atomicAdd(&h2acc[b * 512 + j], acc[b]);
}

__global__ __launch_bounds__(256) void temb3_kernel(
    const float* __restrict__ h2acc, const float* __restrict__ b2,
    const float* __restrict__ Wt, float* __restrict__ inj)
{
    int ks = blockIdx.x;
    __shared__ float sws[8][64];
    int tid = threadIdx.x;
    for (int i = tid; i < 512; i += 256) {
        int b = i >> 6, kk = i & 63;
        int k = ks * 64 + kk;
        float v = h2acc[b * 512 + k] + b2[k];
        sws[b][kk] = v / (1.0f + expf(-v));
    }
    __syncthreads();
    int b = tid >> 5, c = tid & 31;
    float acc = 0.f;
    for (int kk = 0; kk < 64; ++kk)
        acc += sws[b][kk] * Wt[(ks * 64 + kk) * 32 + c];
    atomicAdd(&inj[tid], acc);
}

// ---- hist: block per chunk (grid NCHP); coarse LDS histogram --------------
// counts layout: counts[c * NBC + b]
__global__ __launch_bounds__(256) void hist_kernel(
    const int* __restrict__ ei, int* __restrict__ counts, int E, int NBC)
{
    __shared__ int h[NBCMAX];
    int tid = threadIdx.x;
    int c = blockIdx.x;
    for (int i = tid; i < NBC; i += 256) h[i] = 0;
    __syncthreads();
    int s = c * CH, e = min(s + CH, E);
    for (int i = s + tid; i < e; i += 256)
        atomicAdd(&h[ei[i] >> CWSH], 1);
    __syncthreads();
    int* row = counts + (size_t)c * NBC;
    for (int i = tid; i < NBC; i += 256) row[i] = h[i];
}

// ---- scanA: per-block sums over j = (b<<LOGC)+c order ---------------------
__global__ __launch_bounds__(256) void scanA_kernel(
    const int* __restrict__ counts, int* __restrict__ bsums,
    int M, int NBC, int LOGC)
{
    __shared__ int s[256];
    int tid = threadIdx.x;
    int j0 = blockIdx.x * 4096 + tid * 16;
    int maskC = (1 << LOGC) - 1;
    int p = 0;
#pragma unroll
    for (int k = 0; k < 16; ++k) {
        int j = j0 + k;
        if (j < M) {
            int b = j >> LOGC, c = j & maskC;
            p += counts[(size_t)c * NBC + b];
        }
    }
    s[tid] = p; __syncthreads();
    for (int off = 128; off > 0; off >>= 1) {
        if (tid < off) s[tid] += s[tid + off];
        __syncthreads();
    }
    if (tid == 0) bsums[blockIdx.x] = s[0];
}

// ---- scanB: exclusive scan of block sums (single block, <=1024) -----------
__global__ __launch_bounds__(1024) void scanB_kernel(
    int* __restrict__ bsums, int* __restrict__ bstart, int nblk, int NBC, int E)
{
    __shared__ int s[1024];
    int tid = threadIdx.x;
    int v = (tid < nblk) ? bsums[tid] : 0;
    s[tid] = v; __syncthreads();
    for (int off = 1; off < 1024; off <<= 1) {
        int u = (tid >= off) ? s[tid - off] : 0;
        __syncthreads();
        s[tid] += u;
        __syncthreads();
    }
    if (tid < nblk) bsums[tid] = s[tid] - v;          // exclusive
    if (tid == 0) bstart[NBC] = E;
}

// ---- scanC: exact base for every (bucket, chunk) region + bstart ----------
// base layout: base[(b<<LOGC)+c] (linear in scan order)
__global__ __launch_bounds__(256) void scanC_kernel(
    const int* __restrict__ counts, const int* __restrict__ bsums,
    int* __restrict__ base, int* __restrict__ bstart,
    int M, int NBC, int LOGC)
{
    __shared__ int s[256];
    int tid = threadIdx.x;
    int j0 = blockIdx.x * 4096 + tid * 16;
    int maskC = (1 << LOGC) - 1;
    int v[16]; int p = 0;
#pragma unroll
    for (int k = 0; k < 16; ++k) {
        int j = j0 + k;
        v[k] = 0;
        if (j < M) {
            int b = j >> LOGC, c = j & maskC;
            v[k] = counts[(size_t)c * NBC + b];
        }
        p += v[k];
    }
    s[tid] = p; __syncthreads();
    for (int off = 1; off < 256; off <<= 1) {
        int u = (tid >= off) ? s[tid - off] : 0;
        __syncthreads();
        s[tid] += u;
        __syncthreads();
    }
    int run = bsums[blockIdx.x] + (s[tid] - p);
#pragma unroll
    for (int k = 0; k < 16; ++k) {
        int j = j0 + k;
        if (j < M) {
            base[j] = run;
            if ((j & maskC) == 0) bstart[j >> LOGC] = run;
            run += v[k];
        }
    }
}

// ---- scatter: block per chunk; XCD swizzle; coarse LDS cursors ------------
// rec = { col | T<<19 | nt<<22 , row & (CW-1) } (8B)
__global__ __launch_bounds__(512) void scatter_kernel(
    const int* __restrict__ ei, const int* __restrict__ etype,
    const int* __restrict__ ntype, const int* __restrict__ base,
    uint2* __restrict__ rec, int E, int NBC, int LOGC)
{
    __shared__ int cur[NBCMAX];
    int tid = threadIdx.x;
    // bijective XCD swizzle: consecutive chunks -> same XCD so straddle lines
    // between adjacent regions stay in one XCD's L2.
    int nwg = gridDim.x;
    int q = nwg >> 3, r = nwg & 7;
    int xcd = blockIdx.x & 7, idx = blockIdx.x >> 3;
    int c = (xcd < r) ? xcd * (q + 1) + idx
                      : r * (q + 1) + (xcd - r) * q + idx;
    for (int b = tid; b < NBC; b += 512)
        cur[b] = base[((size_t)b << LOGC) + c];
    __syncthreads();
    int s = c * CH, e = min(s + CH, E);
    for (int i = s + tid; i < e; i += 512) {
        int row = ei[i], col = ei[E + i];
        int T = etype[i], nt = ntype[col];
        int b = row >> CWSH;
        int slot = atomicAdd(&cur[b], 1);
        uint2 rc;
        rc.x = (unsigned)col | ((unsigned)T << 19) | ((unsigned)nt << 22);
        rc.y = (unsigned)(row & (CW - 1));
        rec[slot] = rc;
    }
}

// ---- consume: block per coarse bucket; in-LDS fine sort; window sweep -----
__global__ __launch_bounds__(512) void consume_kernel(
    const int* __restrict__ bstart, const uint2* __restrict__ rec,
    const float* __restrict__ x, const float* __restrict__ Wc,
    const int* __restrict__ batch, const float* __restrict__ inj,
    float* __restrict__ out, int N)
{
    __shared__ float Ws[55 * 32];       //  7040 B
    __shared__ float tile[WSZ * 57];    // 29184 B (stride 57: odd -> banks)
    __shared__ uint2 recs[RECMAX];      // 104 KB, window-sorted records
    __shared__ int seg[NW + 1];
    __shared__ int cur[NW];
    int tid = threadIdx.x;
    int b = blockIdx.x;

    for (int i = tid; i < 55 * 32; i += 512) Ws[i] = Wc[i];
    if (tid < NW) cur[tid] = 0;
    __syncthreads();

    int s = bstart[b], e = bstart[b + 1];
    int n = e - s;
    bool inLds = (n <= RECMAX);

    if (inLds) {
        // Phase A: 16-way window histogram
        for (int i = s + tid; i < e; i += 512) {
            unsigned w = rec[i].y >> 7;           // window = lrow / 128
            atomicAdd(&cur[w], 1);
        }
        __syncthreads();
        if (tid == 0) {
            int run = 0;
#pragma unroll
            for (int w = 0; w < NW; ++w) { seg[w] = run; run += cur[w]; }
            seg[NW] = run;
        }
        __syncthreads();
        if (tid < NW) cur[tid] = seg[tid];
        __syncthreads();
        // Phase B: scatter into sorted LDS buffer (global re-read is L2-hot)
        for (int i = s + tid; i < e; i += 512) {
            uint2 rc = rec[i];
            unsigned w = rc.y >> 7;
            int slot = atomicAdd(&cur[w], 1);
            recs[slot] = rc;
        }
        __syncthreads();
    }

    // Phase C: per-window accumulate + dense mix + coalesced store
    for (int w = 0; w < NW; ++w) {
        int node0 = b * CW + w * WSZ;
        if (node0 >= N) break;
        // zero tile (float4)
        for (int i = tid; i < WSZ * 57 / 4; i += 512)
            ((float4*)tile)[i] = make_float4(0.f, 0.f, 0.f, 0.f);
        __syncthreads();
        if (inLds) {
            for (int j = seg[w] + tid; j < seg[w + 1]; j += 512) {
                uint2 rc = recs[j];
                int col  = rc.x & 0x7FFFF;
                int T    = (rc.x >> 19) & 7;
                int nt   = (rc.x >> 22) & 7;
                int lrow = (int)(rc.y & (WSZ - 1));
                float4 xv = ((const float4*)x)[col];
                float* tr = tile + lrow * 57 + T * 11;
                atomicAdd(tr + 0, xv.x);
                atomicAdd(tr + 1, xv.y);
                atomicAdd(tr + 2, xv.z);
                atomicAdd(tr + 3, xv.w);
                atomicAdd(tr + 4 + nt, 1.0f);
            }
        } else {
            // overflow fallback (adversarial skew): scan whole region per window
            for (int i = s + tid; i < e; i += 512) {
                uint2 rc = rec[i];
                if ((int)(rc.y >> 7) != w) continue;
                int col  = rc.x & 0x7FFFF;
                int T    = (rc.x >> 19) & 7;
                int nt   = (rc.x >> 22) & 7;
                int lrow = (int)(rc.y & (WSZ - 1));
                float4 xv = ((const float4*)x)[col];
                float* tr = tile + lrow * 57 + T * 11;
                atomicAdd(tr + 0, xv.x);
                atomicAdd(tr + 1, xv.y);
                atomicAdd(tr + 2, xv.z);
                atomicAdd(tr + 3, xv.w);
                atomicAdd(tr + 4 + nt, 1.0f);
            }
        }
        __syncthreads();
        int nodes = N - node0; if (nodes > WSZ) nodes = WSZ;
        for (int oi = tid; oi < nodes * 8; oi += 512) {
            int nl = oi >> 3, cq = oi & 7;
            int nn = node0 + nl;
            const float* ar = tile + nl * 57;
            float4 acc = {0.f, 0.f, 0.f, 0.f};
#pragma unroll 5
            for (int f = 0; f < 55; ++f) {
                float a = ar[f];
                float4 wv = *(const float4*)(Ws + f * 32 + cq * 4);
                acc.x += a * wv.x;
                acc.y += a * wv.y;
                acc.z += a * wv.z;
                acc.w += a * wv.w;
            }
            int bb = batch[nn];
            float4 iv = ((const float4*)inj)[bb * 8 + cq];
            float4 o;
            o.x = iv.x + 0.2f * acc.x;
            o.y = iv.y + 0.2f * acc.y;
            o.z = iv.z + 0.2f * acc.z;
            o.w = iv.w + 0.2f * acc.w;
            ((float4*)out)[(size_t)nn * 8 + cq] = o;
        }
        __syncthreads();
    }
}

// ---- fallback (guards fail): out init + direct atomic scatter -------------
__global__ __launch_bounds__(256) void init_kernel(
    const int* __restrict__ batch_id, const float* __restrict__ inj,
    float4* __restrict__ out, int N)
{
    int gid = blockIdx.x * 256 + threadIdx.x;
    if (gid >= N * 8) return;
    int n = gid >> 3, q = gid & 7;
    int b = batch_id[n];
    out[gid] = ((const float4*)inj)[b * 8 + q];
}

__global__ __launch_bounds__(256) void edge_direct_kernel(
    const int* __restrict__ ei, const int* __restrict__ etype,
    const int* __restrict__ ntype, const float* __restrict__ x,
    const float* __restrict__ Wc, float* __restrict__ out, int E)
{
    __shared__ float Ws[55 * 32];
    for (int i = threadIdx.x; i < 55 * 32; i += 256) Ws[i] = Wc[i];
    __syncthreads();
    unsigned total = (unsigned)E * 32u;
    unsigned stride = gridDim.x * 256u;
    for (unsigned idx = blockIdx.x * 256u + threadIdx.x; idx < total;
         idx += stride) {
        int e = (int)(idx >> 5);
        int c = (int)(idx & 31);
        int row = ei[e];
        int col = ei[E + e];
        int T = etype[e];
        int nt = ntype[col];
        float4 xv = ((const float4*)x)[col];
        const float* wb = Ws + T * 352;
        float y = xv.x * wb[c] + xv.y * wb[32 + c] + xv.z * wb[64 + c] +
                  xv.w * wb[96 + c] + wb[(4 + nt) * 32 + c];
        atomicAdd(out + (size_t)row * 32 + c, y * 0.2f);
    }
}

extern "C" void kernel_launch(void* const* d_in, const int* in_sizes, int n_in,
                              void* d_out, int out_size, void* d_ws, size_t ws_size,
                              hipStream_t stream) {
    const float* x     = (const float*)d_in[0];   // [N,4]
    const float* t     = (const float*)d_in[1];   // [8]
    const int*   ei    = (const int*)d_in[2];     // [2,E]
    const int*   etype = (const int*)d_in[3];     // [E]
    const int*   ntype = (const int*)d_in[4];     // [N]
    const int*   batch = (const int*)d_in[5];     // [N]
    const float* Wc    = (const float*)d_in[6];   // [55,32]
    const float* W1    = (const float*)d_in[7];   // [128,512]
    const float* b1    = (const float*)d_in[8];   // [512]
    const float* W2    = (const float*)d_in[9];   // [512,512]
    const float* b2    = (const float*)d_in[10];  // [512]
    const float* Wt    = (const float*)d_in[11];  // [512,32]
    float* out = (float*)d_out;

    int E = in_sizes[3];
    int N = in_sizes[4];

    int NBC = (N + CW - 1) >> CWSH;               // coarse buckets
    int NCH = (E + CH - 1) / CH;                  // real edge chunks
    int NCHP = 1, LOGC = 0;                       // padded to pow2
    while (NCHP < NCH) { NCHP <<= 1; ++LOGC; }
    size_t M = (size_t)NBC << LOGC;               // scan length
    int nblkA = (int)((M + 4095) / 4096);

    // ws layout (4-byte units)
    float* ws     = (float*)d_ws;
    float* h1acc  = ws;                           // 4096 (fallback only)
    float* h2acc  = ws + 4096;                    // 4096 (fallback only)
    float* inj    = ws + 8192;                    // 256
    int*   counts = (int*)(ws + 8448);            // M  (counts[c][b])
    int*   base   = counts + M;                   // M  (base[(b<<LOGC)+c])
    int*   bsums  = base + M;                     // 1024
    int*   bstart = bsums + 1024;                 // NBC+1
    size_t recOff = 8448 + 2 * M + 1024 + NBC + 1;
    recOff = (recOff + 1) & ~(size_t)1;           // 8B align
    uint2* rec    = (uint2*)(ws + recOff);        // E records (8B)

    size_t needBytes = (recOff + 2 * (size_t)E) * 4;
    bool okay = (NBC <= NBCMAX) && (nblkA <= 1024) && (ws_size >= needBytes) &&
                (N <= 524288) && (M < (size_t)1 << 30);

    if (okay) {
        temb_fused_kernel<<<8, 256, 0, stream>>>(t, W1, b1, W2, b2, Wt, inj);

        hist_kernel<<<NCHP, 256, 0, stream>>>(ei, counts, E, NBC);
        scanA_kernel<<<nblkA, 256, 0, stream>>>(counts, bsums, (int)M, NBC,
                                                LOGC);
        scanB_kernel<<<1, 1024, 0, stream>>>(bsums, bstart, nblkA, NBC, E);
        scanC_kernel<<<nblkA, 256, 0, stream>>>(counts, bsums, base, bstart,
                                                (int)M, NBC, LOGC);
        scatter_kernel<<<NCH, 512, 0, stream>>>(ei, etype, ntype, base, rec,
                                                E, NBC, LOGC);
        consume_kernel<<<NBC, 512, 0, stream>>>(bstart, rec, x, Wc, batch,
                                                inj, out, N);
    } else {
        hipMemsetAsync(d_ws, 0, 8448 * 4, stream);
        temb1_kernel<<<32, 64, 0, stream>>>(t, W1, h1acc);
        temb2_kernel<<<64, 64, 0, stream>>>(h1acc, b1, W2, h2acc);
        temb3_kernel<<<8, 256, 0, stream>>>(h2acc, b2, Wt, inj);
        init_kernel<<<(N * 8 + 255) / 256, 256, 0, stream>>>(
            batch, inj, (float4*)out, N);
        edge_direct_kernel<<<16384, 256, 0, stream>>>(
            ei, etype, ntype, x, Wc, out, E);
    }
}